// Round 17
// baseline (327.916 us; speedup 1.0000x reference)
//
#include <hip/hip_runtime.h>
#include <math.h>

#define KD 200
#define CD 352
#define NITER 24
#define LMB 0.01f

__device__ __forceinline__ float4 ld4(const float* p) { return *(const float4*)p; }
__device__ __forceinline__ void st4(float* p, float4 v) { *(float4*)p = v; }
__device__ __forceinline__ float rdlane(float v, int lane) {
    return __int_as_float(__builtin_amdgcn_readlane(__float_as_int(v), lane));
}

// ---------------- Kernel 1: G = A A^T, R = B A^T (batched, 64x64 tiles) ----------------
__global__ __launch_bounds__(256) void gemm_gr_kernel(
    const float* __restrict__ A, const float* __restrict__ B,
    float* __restrict__ G, float* __restrict__ R)
{
    __shared__ __align__(16) float Ms[16][72];   // [k][m]
    __shared__ __align__(16) float Ns[16][72];   // [k][n]
    const int tid = threadIdx.x;
    const int z = blockIdx.z;
    const int b = z >> 1, which = z & 1;
    const float* __restrict__ Xb = (which ? B : A) + (size_t)b * KD * CD;
    const float* __restrict__ Ab = A + (size_t)b * KD * CD;
    float* __restrict__ O = (which ? R : G) + (size_t)b * KD * KD;
    const int tileM = blockIdx.y * 64;
    const int tileN = blockIdx.x * 64;

    const int lm = tid >> 2;             // 0..63
    const int kq = (tid & 3) * 4;        // 0,4,8,12
    const int rowM = min(tileM + lm, KD - 1);
    const int rowN = min(tileN + lm, KD - 1);
    const float* __restrict__ Xrow = Xb + (size_t)rowM * CD;
    const float* __restrict__ Arow = Ab + (size_t)rowN * CD;

    const int ty = tid >> 4, tx = tid & 15;
    const int m0 = ty * 4, n0 = tx * 4;

    float acc[4][4] = {};
    for (int kk = 0; kk < CD; kk += 16) {
        const float4 vx = ld4(Xrow + kk + kq);
        const float4 va = ld4(Arow + kk + kq);
        __syncthreads();
        Ms[kq + 0][lm] = vx.x; Ms[kq + 1][lm] = vx.y;
        Ms[kq + 2][lm] = vx.z; Ms[kq + 3][lm] = vx.w;
        Ns[kq + 0][lm] = va.x; Ns[kq + 1][lm] = va.y;
        Ns[kq + 2][lm] = va.z; Ns[kq + 3][lm] = va.w;
        __syncthreads();
        #pragma unroll
        for (int k = 0; k < 16; ++k) {
            const float4 am = ld4(&Ms[k][m0]);
            const float4 an = ld4(&Ns[k][n0]);
            acc[0][0] = fmaf(am.x, an.x, acc[0][0]);
            acc[0][1] = fmaf(am.x, an.y, acc[0][1]);
            acc[0][2] = fmaf(am.x, an.z, acc[0][2]);
            acc[0][3] = fmaf(am.x, an.w, acc[0][3]);
            acc[1][0] = fmaf(am.y, an.x, acc[1][0]);
            acc[1][1] = fmaf(am.y, an.y, acc[1][1]);
            acc[1][2] = fmaf(am.y, an.z, acc[1][2]);
            acc[1][3] = fmaf(am.y, an.w, acc[1][3]);
            acc[2][0] = fmaf(am.z, an.x, acc[2][0]);
            acc[2][1] = fmaf(am.z, an.y, acc[2][1]);
            acc[2][2] = fmaf(am.z, an.z, acc[2][2]);
            acc[2][3] = fmaf(am.z, an.w, acc[2][3]);
            acc[3][0] = fmaf(am.w, an.x, acc[3][0]);
            acc[3][1] = fmaf(am.w, an.y, acc[3][1]);
            acc[3][2] = fmaf(am.w, an.z, acc[3][2]);
            acc[3][3] = fmaf(am.w, an.w, acc[3][3]);
        }
    }
    const int gn = tileN + n0;
    if (gn < KD) {
        #pragma unroll
        for (int i = 0; i < 4; ++i) {
            const int gm = tileM + m0 + i;
            if (gm < KD)
                st4(&O[(size_t)gm * KD + gn],
                    make_float4(acc[i][0], acc[i][1], acc[i][2], acc[i][3]));
        }
    }
}

// ------------- Kernel 2: batched standard PCG, 4 systems/block, 400 blocks -------------
// NSYS=4 so TWO blocks co-reside per CU (LDS ~30 KB, VGPR < 128): independent blocks
// interleave across each other's barriers, hiding the serial/barrier stall that
// dominated all NSYS=8 variants (70% stall at 1 block/CU). Phase structure is R12's
// proven 4-barrier standard PCG (direct dots; Gear diverged in fp32 — R9). Wave w owns
// 25 contiguous columns; its p-slice is read via two branch-free LDS loads (pv0/pv1,
// ALL lanes — exec-mask/readlane hazard, R9/R10) and broadcast via readlane. State
// thread tid<400 = (row r=tid>>1, sq=tid&1) owns systems sq*2..sq*2+1 in registers.
// NO large register caches (R14/R16: >128 VGPR demand spills to scratch, 100x FETCH).
__global__ __launch_bounds__(512) void cg_kernel(
    const float* __restrict__ G, const float* __restrict__ R,
    const float* __restrict__ ex, const float* __restrict__ ey,
    float* __restrict__ out)
{
    __shared__ __align__(16) float P[864];             // p[c][s]=P[c*4+s], c<200,s<4 (+pad)
    __shared__ __align__(16) float PART[8 * KD * 4];   // [w][row][s], 25.6 KB
    __shared__ float WP1[8][4];                        // pq partials [w][sys]
    __shared__ float WP2[8][4];                        // rz partials
    __shared__ float red8[8];

    const int tid = threadIdx.x;
    const int w = tid >> 6, l = tid & 63;
    const int blk = blockIdx.x;
    const int b = blk / 50;                // 50 blocks per batch
    const int i0 = (blk - b * 50) * 4;
    const int bK = b * KD;
    const float* __restrict__ Gb = G + (size_t)b * KD * KD;

    // ---- scale = max(ex[b,:], ey[b,:]) ----
    float mxv = 0.f;
    if (tid < KD) mxv = fmaxf(ex[bK + tid], ey[bK + tid]);
    #pragma unroll
    for (int off = 32; off > 0; off >>= 1)
        mxv = fmaxf(mxv, __shfl_down(mxv, off, 64));
    if (l == 0) red8[w] = mxv;
    __syncthreads();
    float scale = red8[0];
    #pragma unroll
    for (int wv = 1; wv < 8; ++wv) scale = fmaxf(scale, red8[wv]);
    const float inv_scale = 1.0f / scale;

    const bool mact = (l < 50);
    const int gcol = mact ? l : 49;        // lanes 50..63 duplicate row-group 49 (discarded)

    // ---- state init (registers): thread owns (row r, systems sq*2..sq*2+1) ----
    const bool stid = tid < 400;
    const int r = tid >> 1, sq = tid & 1;
    float lam[2], dinv[2], rr[2], xx[2], pp[2], rz4[2];
    if (stid) {
        const float exj = ex[bK + r] * inv_scale;
        const float e1 = sqrtf(exj);
        const float gdiag = Gb[(size_t)r * KD + r];
        const float* __restrict__ Rb = R + (size_t)(bK + i0 + sq * 2) * KD + r;
        #pragma unroll
        for (int j = 0; j < 2; ++j) {
            const float eyi = ey[bK + i0 + sq * 2 + j] * inv_scale;
            const float e2 = sqrtf(eyi);
            const float dn = exj + eyi;
            const float re = e2 - e1;
            lam[j] = LMB * ((re * re + 1.f) / (dn * dn));
            dinv[j] = 1.f / (gdiag + lam[j]);
            rr[j] = Rb[(size_t)j * KD];
            pp[j] = rr[j] * dinv[j];      // p0 = z0
            xx[j] = 0.f;
        }
        *(float2*)&P[r * 4 + sq * 2] = make_float2(pp[0], pp[1]);
    }
    // rz0 partials
    {
        float vg[2];
        #pragma unroll
        for (int j = 0; j < 2; ++j) vg[j] = stid ? rr[j] * pp[j] : 0.f;
        #pragma unroll
        for (int off = 2; off < 64; off <<= 1)
            #pragma unroll
            for (int j = 0; j < 2; ++j) vg[j] += __shfl_xor(vg[j], off, 64);
        if (l < 2) {
            #pragma unroll
            for (int j = 0; j < 2; ++j) WP2[w][l * 2 + j] = vg[j];
        }
    }
    __syncthreads();                       // P + rz0 partials ready
    if (stid) {
        #pragma unroll
        for (int j = 0; j < 2; ++j) {
            float s = 0.f;
            #pragma unroll
            for (int w8 = 0; w8 < 8; ++w8) s += WP2[w8][sq * 2 + j];
            rz4[j] = s;
        }
    }

    // ================= standard PCG main loop (4 barriers/iter) =================
    for (int k = 0; k < NITER; ++k) {
        __syncthreads();                   // B1: P stable, WP consumed

        // ---- matvec partials over this wave's 25 columns (25w..25w+24) ----
        float acc[4][4];                   // [row group][system]
        #pragma unroll
        for (int j = 0; j < 4; ++j)
            #pragma unroll
            for (int s = 0; s < 4; ++s) acc[j][s] = 0.f;

        const float pv0 = P[w * 100 + l];        // cols 25w..25w+15 (ALL lanes load)
        const float pv1 = P[w * 100 + 64 + l];   // cols 25w+16..25w+24 (lanes 0..35 used)
        const float* __restrict__ gp = Gb + (size_t)(25 * w) * KD + gcol;
        #pragma unroll
        for (int dc = 0; dc < 25; ++dc) {
            const float g0v = gp[0];
            const float g1v = gp[50];
            const float g2v = gp[100];
            const float g3v = gp[150];
            #pragma unroll
            for (int s = 0; s < 4; ++s) {
                const float ps = (dc < 16) ? rdlane(pv0, dc * 4 + s)
                                           : rdlane(pv1, (dc - 16) * 4 + s);
                acc[0][s] = fmaf(g0v, ps, acc[0][s]);
                acc[1][s] = fmaf(g1v, ps, acc[1][s]);
                acc[2][s] = fmaf(g2v, ps, acc[2][s]);
                acc[3][s] = fmaf(g3v, ps, acc[3][s]);
            }
            gp += KD;
        }
        if (mact) {
            #pragma unroll
            for (int j = 0; j < 4; ++j)
                st4(&PART[w * (KD * 4) + (50 * j + l) * 4],
                    make_float4(acc[j][0], acc[j][1], acc[j][2], acc[j][3]));
        }
        __syncthreads();                   // B2: PART ready

        // ---- q = A p (combine) + pq partials ----
        float qq[2], vq[2];
        if (stid) {
            float s0 = 0.f, s1 = 0.f;
            #pragma unroll
            for (int w8 = 0; w8 < 8; ++w8) {
                const float2 f = *(const float2*)&PART[w8 * (KD * 4) + r * 4 + sq * 2];
                s0 += f.x; s1 += f.y;
            }
            qq[0] = fmaf(lam[0], pp[0], s0);
            qq[1] = fmaf(lam[1], pp[1], s1);
            vq[0] = pp[0] * qq[0];
            vq[1] = pp[1] * qq[1];
        } else {
            qq[0] = qq[1] = 0.f; vq[0] = vq[1] = 0.f;
        }
        #pragma unroll
        for (int off = 2; off < 64; off <<= 1)
            #pragma unroll
            for (int j = 0; j < 2; ++j) vq[j] += __shfl_xor(vq[j], off, 64);
        if (l < 2) {
            #pragma unroll
            for (int j = 0; j < 2; ++j) WP1[w][l * 2 + j] = vq[j];
        }
        __syncthreads();                   // B3: pq ready

        // ---- alpha, x/r update, rz partials ----
        float vr[2];
        if (stid) {
            #pragma unroll
            for (int j = 0; j < 2; ++j) {
                float pq = 0.f;
                #pragma unroll
                for (int w8 = 0; w8 < 8; ++w8) pq += WP1[w8][sq * 2 + j];
                const float alpha = rz4[j] / pq;
                xx[j] = fmaf(alpha, pp[j], xx[j]);
                rr[j] = fmaf(-alpha, qq[j], rr[j]);
                vr[j] = rr[j] * rr[j] * dinv[j];
            }
        } else {
            vr[0] = vr[1] = 0.f;
        }
        #pragma unroll
        for (int off = 2; off < 64; off <<= 1)
            #pragma unroll
            for (int j = 0; j < 2; ++j) vr[j] += __shfl_xor(vr[j], off, 64);
        if (l < 2) {
            #pragma unroll
            for (int j = 0; j < 2; ++j) WP2[w][l * 2 + j] = vr[j];
        }
        __syncthreads();                   // B4: rz ready

        // ---- beta, p update ----
        if (stid) {
            #pragma unroll
            for (int j = 0; j < 2; ++j) {
                float rzn = 0.f;
                #pragma unroll
                for (int w8 = 0; w8 < 8; ++w8) rzn += WP2[w8][sq * 2 + j];
                const float beta = rzn / rz4[j];
                rz4[j] = rzn;
                pp[j] = fmaf(beta, pp[j], rr[j] * dinv[j]);   // p = z + beta p
            }
            *(float2*)&P[r * 4 + sq * 2] = make_float2(pp[0], pp[1]);
        }
    }

    // ---- store x ----
    if (stid) {
        float* __restrict__ Ob = out + (size_t)(bK + i0 + sq * 2) * KD + r;
        Ob[0]  = xx[0];
        Ob[KD] = xx[1];
    }
}

extern "C" void kernel_launch(void* const* d_in, const int* in_sizes, int n_in,
                              void* d_out, int out_size, void* d_ws, size_t ws_size,
                              hipStream_t stream) {
    const float* A  = (const float*)d_in[0];
    const float* B  = (const float*)d_in[1];
    const float* ex = (const float*)d_in[2];
    const float* ey = (const float*)d_in[3];
    float* out = (float*)d_out;

    float* G = (float*)d_ws;
    float* R = G + 8 * KD * KD;

    dim3 grid1(4, 4, 16);
    gemm_gr_kernel<<<grid1, 256, 0, stream>>>(A, B, G, R);

    cg_kernel<<<400, 512, 0, stream>>>(G, R, ex, ey, out);
}

// Round 19
// 212.911 us; speedup vs baseline: 1.5402x; 1.5402x over previous
//
#include <hip/hip_runtime.h>
#include <math.h>

#define KD 200
#define CD 352
#define NITER 24
#define LMB 0.01f

__device__ __forceinline__ float4 ld4(const float* p) { return *(const float4*)p; }
__device__ __forceinline__ void st4(float* p, float4 v) { *(float4*)p = v; }
__device__ __forceinline__ float rdlane(float v, int lane) {
    return __int_as_float(__builtin_amdgcn_readlane(__float_as_int(v), lane));
}

// ---------------- Kernel 1: G = A A^T, R = B A^T (batched, 64x64 tiles) ----------------
__global__ __launch_bounds__(256) void gemm_gr_kernel(
    const float* __restrict__ A, const float* __restrict__ B,
    float* __restrict__ G, float* __restrict__ R)
{
    __shared__ __align__(16) float Ms[16][72];   // [k][m]
    __shared__ __align__(16) float Ns[16][72];   // [k][n]
    const int tid = threadIdx.x;
    const int z = blockIdx.z;
    const int b = z >> 1, which = z & 1;
    const float* __restrict__ Xb = (which ? B : A) + (size_t)b * KD * CD;
    const float* __restrict__ Ab = A + (size_t)b * KD * CD;
    float* __restrict__ O = (which ? R : G) + (size_t)b * KD * KD;
    const int tileM = blockIdx.y * 64;
    const int tileN = blockIdx.x * 64;

    const int lm = tid >> 2;             // 0..63
    const int kq = (tid & 3) * 4;        // 0,4,8,12
    const int rowM = min(tileM + lm, KD - 1);
    const int rowN = min(tileN + lm, KD - 1);
    const float* __restrict__ Xrow = Xb + (size_t)rowM * CD;
    const float* __restrict__ Arow = Ab + (size_t)rowN * CD;

    const int ty = tid >> 4, tx = tid & 15;
    const int m0 = ty * 4, n0 = tx * 4;

    float acc[4][4] = {};
    for (int kk = 0; kk < CD; kk += 16) {
        const float4 vx = ld4(Xrow + kk + kq);
        const float4 va = ld4(Arow + kk + kq);
        __syncthreads();
        Ms[kq + 0][lm] = vx.x; Ms[kq + 1][lm] = vx.y;
        Ms[kq + 2][lm] = vx.z; Ms[kq + 3][lm] = vx.w;
        Ns[kq + 0][lm] = va.x; Ns[kq + 1][lm] = va.y;
        Ns[kq + 2][lm] = va.z; Ns[kq + 3][lm] = va.w;
        __syncthreads();
        #pragma unroll
        for (int k = 0; k < 16; ++k) {
            const float4 am = ld4(&Ms[k][m0]);
            const float4 an = ld4(&Ns[k][n0]);
            acc[0][0] = fmaf(am.x, an.x, acc[0][0]);
            acc[0][1] = fmaf(am.x, an.y, acc[0][1]);
            acc[0][2] = fmaf(am.x, an.z, acc[0][2]);
            acc[0][3] = fmaf(am.x, an.w, acc[0][3]);
            acc[1][0] = fmaf(am.y, an.x, acc[1][0]);
            acc[1][1] = fmaf(am.y, an.y, acc[1][1]);
            acc[1][2] = fmaf(am.y, an.z, acc[1][2]);
            acc[1][3] = fmaf(am.y, an.w, acc[1][3]);
            acc[2][0] = fmaf(am.z, an.x, acc[2][0]);
            acc[2][1] = fmaf(am.z, an.y, acc[2][1]);
            acc[2][2] = fmaf(am.z, an.z, acc[2][2]);
            acc[2][3] = fmaf(am.z, an.w, acc[2][3]);
            acc[3][0] = fmaf(am.w, an.x, acc[3][0]);
            acc[3][1] = fmaf(am.w, an.y, acc[3][1]);
            acc[3][2] = fmaf(am.w, an.z, acc[3][2]);
            acc[3][3] = fmaf(am.w, an.w, acc[3][3]);
        }
    }
    const int gn = tileN + n0;
    if (gn < KD) {
        #pragma unroll
        for (int i = 0; i < 4; ++i) {
            const int gm = tileM + m0 + i;
            if (gm < KD)
                st4(&O[(size_t)gm * KD + gn],
                    make_float4(acc[i][0], acc[i][1], acc[i][2], acc[i][3]));
        }
    }
}

// ------------- Kernel 2: batched standard PCG, 4 systems/block, 400 blocks -------------
// NSYS=4 (mapping correctness verified by R17's passing run) so TWO blocks co-reside
// per CU (LDS ~29.4 KB, VGPR < 128): independent blocks interleave across each other's
// barriers, hiding the ~70% serial/barrier stall measured at 1 block/CU.
// Matvec uses R12's PROVEN access pattern: per 8-column chunk, one branch-free LDS
// load `pv` at a RUNTIME address, then readlane with COMPILE-TIME lane indices.
// (R18's runtime-index readlane variant miscomputed — never use runtime lane indices.
//  R17's full 25-column unroll hoisted 100 G loads -> >128 VGPR -> scratch spill.)
// Chunk loop is `#pragma unroll 1` so at most 32 G values are live. Direct dots
// (Gear diverged in fp32 — R9). State thread tid<400 = (row r=tid>>1, sq=tid&1)
// owns systems sq*2..sq*2+1 in registers.
__global__ __launch_bounds__(512) void cg_kernel(
    const float* __restrict__ G, const float* __restrict__ R,
    const float* __restrict__ ex, const float* __restrict__ ey,
    float* __restrict__ out)
{
    __shared__ __align__(16) float P[864];             // p[c][s]=P[c*4+s], c<200,s<4 (+pad)
    __shared__ __align__(16) float PART[8 * KD * 4];   // [w][row][s], 25.6 KB
    __shared__ float WP1[8][4];                        // pq partials [w][sys]
    __shared__ float WP2[8][4];                        // rz partials
    __shared__ float red8[8];

    const int tid = threadIdx.x;
    const int w = tid >> 6, l = tid & 63;
    const int blk = blockIdx.x;
    const int b = blk / 50;                // 50 blocks per batch
    const int i0 = (blk - b * 50) * 4;
    const int bK = b * KD;
    const float* __restrict__ Gb = G + (size_t)b * KD * KD;

    // ---- scale = max(ex[b,:], ey[b,:]) ----
    float mxv = 0.f;
    if (tid < KD) mxv = fmaxf(ex[bK + tid], ey[bK + tid]);
    #pragma unroll
    for (int off = 32; off > 0; off >>= 1)
        mxv = fmaxf(mxv, __shfl_down(mxv, off, 64));
    if (l == 0) red8[w] = mxv;
    __syncthreads();
    float scale = red8[0];
    #pragma unroll
    for (int wv = 1; wv < 8; ++wv) scale = fmaxf(scale, red8[wv]);
    const float inv_scale = 1.0f / scale;

    const bool mact = (l < 50);
    const int gcol = mact ? l : 49;        // lanes 50..63 duplicate row-group 49 (discarded)

    // ---- state init (registers): thread owns (row r, systems sq*2..sq*2+1) ----
    const bool stid = tid < 400;
    const int r = tid >> 1, sq = tid & 1;
    float lam[2], dinv[2], rr[2], xx[2], pp[2], rz4[2];
    if (stid) {
        const float exj = ex[bK + r] * inv_scale;
        const float e1 = sqrtf(exj);
        const float gdiag = Gb[(size_t)r * KD + r];
        const float* __restrict__ Rb = R + (size_t)(bK + i0 + sq * 2) * KD + r;
        #pragma unroll
        for (int j = 0; j < 2; ++j) {
            const float eyi = ey[bK + i0 + sq * 2 + j] * inv_scale;
            const float e2 = sqrtf(eyi);
            const float dn = exj + eyi;
            const float re = e2 - e1;
            lam[j] = LMB * ((re * re + 1.f) / (dn * dn));
            dinv[j] = 1.f / (gdiag + lam[j]);
            rr[j] = Rb[(size_t)j * KD];
            pp[j] = rr[j] * dinv[j];      // p0 = z0
            xx[j] = 0.f;
        }
        *(float2*)&P[r * 4 + sq * 2] = make_float2(pp[0], pp[1]);
    }
    // rz0 partials
    {
        float vg[2];
        #pragma unroll
        for (int j = 0; j < 2; ++j) vg[j] = stid ? rr[j] * pp[j] : 0.f;
        #pragma unroll
        for (int off = 2; off < 64; off <<= 1)
            #pragma unroll
            for (int j = 0; j < 2; ++j) vg[j] += __shfl_xor(vg[j], off, 64);
        if (l < 2) {
            #pragma unroll
            for (int j = 0; j < 2; ++j) WP2[w][l * 2 + j] = vg[j];
        }
    }
    __syncthreads();                       // P + rz0 partials ready
    if (stid) {
        #pragma unroll
        for (int j = 0; j < 2; ++j) {
            float s = 0.f;
            #pragma unroll
            for (int w8 = 0; w8 < 8; ++w8) s += WP2[w8][sq * 2 + j];
            rz4[j] = s;
        }
    }

    // ================= standard PCG main loop (4 barriers/iter) =================
    for (int k = 0; k < NITER; ++k) {
        __syncthreads();                   // B1: P stable, WP consumed

        // ---- matvec partials over this wave's 25 columns (25w..25w+24) ----
        float acc[4][4];                   // [row group][system]
        #pragma unroll
        for (int j = 0; j < 4; ++j)
            #pragma unroll
            for (int s = 0; s < 4; ++s) acc[j][s] = 0.f;

        int base = 25 * w;
        #pragma unroll 1                   // rolled: bounds live G values to one chunk
        for (int ch = 0; ch < 3; ++ch) {
            // lanes 0..31 of pv hold cols base..base+7 (x4 sys); ALL lanes load
            // (readlane source must be defined — exec-mask hazard, R9/R10).
            const float pv = P[base * 4 + l];
            const float* __restrict__ gp = Gb + (size_t)base * KD + gcol;
            #pragma unroll
            for (int dc = 0; dc < 8; ++dc) {
                const float g0v = gp[0];
                const float g1v = gp[50];
                const float g2v = gp[100];
                const float g3v = gp[150];
                #pragma unroll
                for (int s = 0; s < 4; ++s) {
                    const float ps = rdlane(pv, dc * 4 + s);   // compile-time index
                    acc[0][s] = fmaf(g0v, ps, acc[0][s]);
                    acc[1][s] = fmaf(g1v, ps, acc[1][s]);
                    acc[2][s] = fmaf(g2v, ps, acc[2][s]);
                    acc[3][s] = fmaf(g3v, ps, acc[3][s]);
                }
                gp += KD;
            }
            base += 8;
        }
        {   // trailing column 25w+24 (base == 25w+24 here)
            const float pv = P[base * 4 + l];   // lanes 0..3 hold its 4 systems
            const float* __restrict__ gp = Gb + (size_t)base * KD + gcol;
            const float g0v = gp[0];
            const float g1v = gp[50];
            const float g2v = gp[100];
            const float g3v = gp[150];
            #pragma unroll
            for (int s = 0; s < 4; ++s) {
                const float ps = rdlane(pv, s);
                acc[0][s] = fmaf(g0v, ps, acc[0][s]);
                acc[1][s] = fmaf(g1v, ps, acc[1][s]);
                acc[2][s] = fmaf(g2v, ps, acc[2][s]);
                acc[3][s] = fmaf(g3v, ps, acc[3][s]);
            }
        }
        if (mact) {
            #pragma unroll
            for (int j = 0; j < 4; ++j)
                st4(&PART[w * (KD * 4) + (50 * j + l) * 4],
                    make_float4(acc[j][0], acc[j][1], acc[j][2], acc[j][3]));
        }
        __syncthreads();                   // B2: PART ready

        // ---- q = A p (combine) + pq partials ----
        float qq[2], vq[2];
        if (stid) {
            float s0 = 0.f, s1 = 0.f;
            #pragma unroll
            for (int w8 = 0; w8 < 8; ++w8) {
                const float2 f = *(const float2*)&PART[w8 * (KD * 4) + r * 4 + sq * 2];
                s0 += f.x; s1 += f.y;
            }
            qq[0] = fmaf(lam[0], pp[0], s0);
            qq[1] = fmaf(lam[1], pp[1], s1);
            vq[0] = pp[0] * qq[0];
            vq[1] = pp[1] * qq[1];
        } else {
            qq[0] = qq[1] = 0.f; vq[0] = vq[1] = 0.f;
        }
        #pragma unroll
        for (int off = 2; off < 64; off <<= 1)
            #pragma unroll
            for (int j = 0; j < 2; ++j) vq[j] += __shfl_xor(vq[j], off, 64);
        if (l < 2) {
            #pragma unroll
            for (int j = 0; j < 2; ++j) WP1[w][l * 2 + j] = vq[j];
        }
        __syncthreads();                   // B3: pq ready

        // ---- alpha, x/r update, rz partials ----
        float vr[2];
        if (stid) {
            #pragma unroll
            for (int j = 0; j < 2; ++j) {
                float pq = 0.f;
                #pragma unroll
                for (int w8 = 0; w8 < 8; ++w8) pq += WP1[w8][sq * 2 + j];
                const float alpha = rz4[j] / pq;
                xx[j] = fmaf(alpha, pp[j], xx[j]);
                rr[j] = fmaf(-alpha, qq[j], rr[j]);
                vr[j] = rr[j] * rr[j] * dinv[j];
            }
        } else {
            vr[0] = vr[1] = 0.f;
        }
        #pragma unroll
        for (int off = 2; off < 64; off <<= 1)
            #pragma unroll
            for (int j = 0; j < 2; ++j) vr[j] += __shfl_xor(vr[j], off, 64);
        if (l < 2) {
            #pragma unroll
            for (int j = 0; j < 2; ++j) WP2[w][l * 2 + j] = vr[j];
        }
        __syncthreads();                   // B4: rz ready

        // ---- beta, p update ----
        if (stid) {
            #pragma unroll
            for (int j = 0; j < 2; ++j) {
                float rzn = 0.f;
                #pragma unroll
                for (int w8 = 0; w8 < 8; ++w8) rzn += WP2[w8][sq * 2 + j];
                const float beta = rzn / rz4[j];
                rz4[j] = rzn;
                pp[j] = fmaf(beta, pp[j], rr[j] * dinv[j]);   // p = z + beta p
            }
            *(float2*)&P[r * 4 + sq * 2] = make_float2(pp[0], pp[1]);
        }
    }

    // ---- store x ----
    if (stid) {
        float* __restrict__ Ob = out + (size_t)(bK + i0 + sq * 2) * KD + r;
        Ob[0]  = xx[0];
        Ob[KD] = xx[1];
    }
}

extern "C" void kernel_launch(void* const* d_in, const int* in_sizes, int n_in,
                              void* d_out, int out_size, void* d_ws, size_t ws_size,
                              hipStream_t stream) {
    const float* A  = (const float*)d_in[0];
    const float* B  = (const float*)d_in[1];
    const float* ex = (const float*)d_in[2];
    const float* ey = (const float*)d_in[3];
    float* out = (float*)d_out;

    float* G = (float*)d_ws;
    float* R = G + 8 * KD * KD;

    dim3 grid1(4, 4, 16);
    gemm_gr_kernel<<<grid1, 256, 0, stream>>>(A, B, G, R);

    cg_kernel<<<400, 512, 0, stream>>>(G, R, ex, ey, out);
}

// Round 20
// 198.929 us; speedup vs baseline: 1.6484x; 1.0703x over previous
//
#include <hip/hip_runtime.h>
#include <math.h>

#define KD 200
#define CD 352
#define NITER 20
#define LMB 0.01f

__device__ __forceinline__ float4 ld4(const float* p) { return *(const float4*)p; }
__device__ __forceinline__ void st4(float* p, float4 v) { *(float4*)p = v; }
__device__ __forceinline__ float rdlane(float v, int lane) {
    return __int_as_float(__builtin_amdgcn_readlane(__float_as_int(v), lane));
}

// ---------------- Kernel 1: G = A A^T, R = B A^T (batched, 64x64 tiles) ----------------
__global__ __launch_bounds__(256) void gemm_gr_kernel(
    const float* __restrict__ A, const float* __restrict__ B,
    float* __restrict__ G, float* __restrict__ R)
{
    __shared__ __align__(16) float Ms[16][72];   // [k][m]
    __shared__ __align__(16) float Ns[16][72];   // [k][n]
    const int tid = threadIdx.x;
    const int z = blockIdx.z;
    const int b = z >> 1, which = z & 1;
    const float* __restrict__ Xb = (which ? B : A) + (size_t)b * KD * CD;
    const float* __restrict__ Ab = A + (size_t)b * KD * CD;
    float* __restrict__ O = (which ? R : G) + (size_t)b * KD * KD;
    const int tileM = blockIdx.y * 64;
    const int tileN = blockIdx.x * 64;

    const int lm = tid >> 2;             // 0..63
    const int kq = (tid & 3) * 4;        // 0,4,8,12
    const int rowM = min(tileM + lm, KD - 1);
    const int rowN = min(tileN + lm, KD - 1);
    const float* __restrict__ Xrow = Xb + (size_t)rowM * CD;
    const float* __restrict__ Arow = Ab + (size_t)rowN * CD;

    const int ty = tid >> 4, tx = tid & 15;
    const int m0 = ty * 4, n0 = tx * 4;

    float acc[4][4] = {};
    for (int kk = 0; kk < CD; kk += 16) {
        const float4 vx = ld4(Xrow + kk + kq);
        const float4 va = ld4(Arow + kk + kq);
        __syncthreads();
        Ms[kq + 0][lm] = vx.x; Ms[kq + 1][lm] = vx.y;
        Ms[kq + 2][lm] = vx.z; Ms[kq + 3][lm] = vx.w;
        Ns[kq + 0][lm] = va.x; Ns[kq + 1][lm] = va.y;
        Ns[kq + 2][lm] = va.z; Ns[kq + 3][lm] = va.w;
        __syncthreads();
        #pragma unroll
        for (int k = 0; k < 16; ++k) {
            const float4 am = ld4(&Ms[k][m0]);
            const float4 an = ld4(&Ns[k][n0]);
            acc[0][0] = fmaf(am.x, an.x, acc[0][0]);
            acc[0][1] = fmaf(am.x, an.y, acc[0][1]);
            acc[0][2] = fmaf(am.x, an.z, acc[0][2]);
            acc[0][3] = fmaf(am.x, an.w, acc[0][3]);
            acc[1][0] = fmaf(am.y, an.x, acc[1][0]);
            acc[1][1] = fmaf(am.y, an.y, acc[1][1]);
            acc[1][2] = fmaf(am.y, an.z, acc[1][2]);
            acc[1][3] = fmaf(am.y, an.w, acc[1][3]);
            acc[2][0] = fmaf(am.z, an.x, acc[2][0]);
            acc[2][1] = fmaf(am.z, an.y, acc[2][1]);
            acc[2][2] = fmaf(am.z, an.z, acc[2][2]);
            acc[2][3] = fmaf(am.z, an.w, acc[2][3]);
            acc[3][0] = fmaf(am.w, an.x, acc[3][0]);
            acc[3][1] = fmaf(am.w, an.y, acc[3][1]);
            acc[3][2] = fmaf(am.w, an.z, acc[3][2]);
            acc[3][3] = fmaf(am.w, an.w, acc[3][3]);
        }
    }
    const int gn = tileN + n0;
    if (gn < KD) {
        #pragma unroll
        for (int i = 0; i < 4; ++i) {
            const int gm = tileM + m0 + i;
            if (gm < KD)
                st4(&O[(size_t)gm * KD + gn],
                    make_float4(acc[i][0], acc[i][1], acc[i][2], acc[i][3]));
        }
    }
}

// ------------- Kernel 2: batched standard PCG, 4 systems/block, 3 barriers/iter -------------
// R19 base (passed, VGPR 56, no spill, conflicts 0) + the R16-verified pq-merge:
// pq = sum_w (p . partial_w) is computed per matvec lane BEFORE barrier B2 (pq is
// linear in q); wave 0 folds lam*p (LAM staged in LDS) into its PART partial so the
// combine sum equals the full q. This removes one of the 4 barriers. Matvec keeps
// R12/R19's proven pattern: rolled 8-column chunks, branch-free runtime-address P
// loads, COMPILE-TIME readlane indices (R18's runtime lane indices miscompute —
// never use). Liveness bounded (<=32 G values; acc[4][4]+vqp[4]) to stay far from
// the 128-VGPR spill cliff (R14/R16/R17). Direct dots (Gear diverged in fp32 — R9).
__global__ __launch_bounds__(512) void cg_kernel(
    const float* __restrict__ G, const float* __restrict__ R,
    const float* __restrict__ ex, const float* __restrict__ ey,
    float* __restrict__ out)
{
    __shared__ __align__(16) float P[864];             // p[c][s]=P[c*4+s], c<200,s<4 (+pad)
    __shared__ __align__(16) float LAM[864];           // lam[c][s], same layout
    __shared__ __align__(16) float PART[8 * KD * 4];   // [w][row][s], 25.6 KB
    __shared__ __align__(16) float WP1[8][4];          // pq partials [w][sys]
    __shared__ float WP2[8][4];                        // rz partials
    __shared__ float red8[8];

    const int tid = threadIdx.x;
    const int w = tid >> 6, l = tid & 63;
    const int blk = blockIdx.x;
    const int b = blk / 50;                // 50 blocks per batch
    const int i0 = (blk - b * 50) * 4;
    const int bK = b * KD;
    const float* __restrict__ Gb = G + (size_t)b * KD * KD;

    // ---- scale = max(ex[b,:], ey[b,:]) ----
    float mxv = 0.f;
    if (tid < KD) mxv = fmaxf(ex[bK + tid], ey[bK + tid]);
    #pragma unroll
    for (int off = 32; off > 0; off >>= 1)
        mxv = fmaxf(mxv, __shfl_down(mxv, off, 64));
    if (l == 0) red8[w] = mxv;
    __syncthreads();
    float scale = red8[0];
    #pragma unroll
    for (int wv = 1; wv < 8; ++wv) scale = fmaxf(scale, red8[wv]);
    const float inv_scale = 1.0f / scale;

    const bool mact = (l < 50);
    const int gcol = mact ? l : 49;        // lanes 50..63 duplicate row-group 49 (discarded)

    // ---- state init (registers): thread owns (row r, systems sq*2..sq*2+1) ----
    const bool stid = tid < 400;
    const int r = tid >> 1, sq = tid & 1;
    float lam[2], dinv[2], rr[2], xx[2], pp[2], rz4[2];
    if (stid) {
        const float exj = ex[bK + r] * inv_scale;
        const float e1 = sqrtf(exj);
        const float gdiag = Gb[(size_t)r * KD + r];
        const float* __restrict__ Rb = R + (size_t)(bK + i0 + sq * 2) * KD + r;
        #pragma unroll
        for (int j = 0; j < 2; ++j) {
            const float eyi = ey[bK + i0 + sq * 2 + j] * inv_scale;
            const float e2 = sqrtf(eyi);
            const float dn = exj + eyi;
            const float re = e2 - e1;
            lam[j] = LMB * ((re * re + 1.f) / (dn * dn));
            dinv[j] = 1.f / (gdiag + lam[j]);
            rr[j] = Rb[(size_t)j * KD];
            pp[j] = rr[j] * dinv[j];      // p0 = z0
            xx[j] = 0.f;
        }
        *(float2*)&P[r * 4 + sq * 2]   = make_float2(pp[0], pp[1]);
        *(float2*)&LAM[r * 4 + sq * 2] = make_float2(lam[0], lam[1]);
    }
    // rz0 partials
    {
        float vg[2];
        #pragma unroll
        for (int j = 0; j < 2; ++j) vg[j] = stid ? rr[j] * pp[j] : 0.f;
        #pragma unroll
        for (int off = 2; off < 64; off <<= 1)
            #pragma unroll
            for (int j = 0; j < 2; ++j) vg[j] += __shfl_xor(vg[j], off, 64);
        if (l < 2) {
            #pragma unroll
            for (int j = 0; j < 2; ++j) WP2[w][l * 2 + j] = vg[j];
        }
    }
    __syncthreads();                       // P, LAM, rz0 partials ready
    if (stid) {
        #pragma unroll
        for (int j = 0; j < 2; ++j) {
            float s = 0.f;
            #pragma unroll
            for (int w8 = 0; w8 < 8; ++w8) s += WP2[w8][sq * 2 + j];
            rz4[j] = s;
        }
    }

    // ================= standard PCG main loop (3 barriers/iter) =================
    for (int k = 0; k < NITER; ++k) {
        __syncthreads();                   // B1: P stable, WP1/WP2 consumed

        // ---- matvec partials over this wave's 25 columns (25w..25w+24) ----
        float acc[4][4];                   // [row group][system]
        #pragma unroll
        for (int j = 0; j < 4; ++j)
            #pragma unroll
            for (int s = 0; s < 4; ++s) acc[j][s] = 0.f;

        int base = 25 * w;
        #pragma unroll 1                   // rolled: bounds live G values to one chunk
        for (int ch = 0; ch < 3; ++ch) {
            const float pv = P[base * 4 + l];   // ALL lanes load (readlane hazard, R9/R10)
            const float* __restrict__ gp = Gb + (size_t)base * KD + gcol;
            #pragma unroll
            for (int dc = 0; dc < 8; ++dc) {
                const float g0v = gp[0];
                const float g1v = gp[50];
                const float g2v = gp[100];
                const float g3v = gp[150];
                #pragma unroll
                for (int s = 0; s < 4; ++s) {
                    const float ps = rdlane(pv, dc * 4 + s);   // compile-time index
                    acc[0][s] = fmaf(g0v, ps, acc[0][s]);
                    acc[1][s] = fmaf(g1v, ps, acc[1][s]);
                    acc[2][s] = fmaf(g2v, ps, acc[2][s]);
                    acc[3][s] = fmaf(g3v, ps, acc[3][s]);
                }
                gp += KD;
            }
            base += 8;
        }
        {   // trailing column 25w+24
            const float pv = P[base * 4 + l];
            const float* __restrict__ gp = Gb + (size_t)base * KD + gcol;
            const float g0v = gp[0];
            const float g1v = gp[50];
            const float g2v = gp[100];
            const float g3v = gp[150];
            #pragma unroll
            for (int s = 0; s < 4; ++s) {
                const float ps = rdlane(pv, s);
                acc[0][s] = fmaf(g0v, ps, acc[0][s]);
                acc[1][s] = fmaf(g1v, ps, acc[1][s]);
                acc[2][s] = fmaf(g2v, ps, acc[2][s]);
                acc[3][s] = fmaf(g3v, ps, acc[3][s]);
            }
        }

        // ---- wave 0 folds lam*p into its partials (diagonal term added once) ----
        if (w == 0 && mact) {
            #pragma unroll
            for (int j = 0; j < 4; ++j) {
                const int row = l + 50 * j;
                const float4 la = ld4(&LAM[row * 4]);
                const float4 pa = ld4(&P[row * 4]);
                acc[j][0] = fmaf(la.x, pa.x, acc[j][0]);
                acc[j][1] = fmaf(la.y, pa.y, acc[j][1]);
                acc[j][2] = fmaf(la.z, pa.z, acc[j][2]);
                acc[j][3] = fmaf(la.w, pa.w, acc[j][3]);
            }
        }

        // ---- per-lane pq partials (pq is linear in q -> fold into this phase) ----
        float vqp[4] = {0.f, 0.f, 0.f, 0.f};
        if (mact) {
            #pragma unroll
            for (int j = 0; j < 4; ++j) {
                const int row = l + 50 * j;
                const float4 pa = ld4(&P[row * 4]);
                vqp[0] = fmaf(pa.x, acc[j][0], vqp[0]);
                vqp[1] = fmaf(pa.y, acc[j][1], vqp[1]);
                vqp[2] = fmaf(pa.z, acc[j][2], vqp[2]);
                vqp[3] = fmaf(pa.w, acc[j][3], vqp[3]);
            }
        }
        #pragma unroll
        for (int off = 1; off < 64; off <<= 1)
            #pragma unroll
            for (int s = 0; s < 4; ++s) vqp[s] += __shfl_xor(vqp[s], off, 64);
        if (l == 0)
            st4(&WP1[w][0], make_float4(vqp[0], vqp[1], vqp[2], vqp[3]));

        if (mact) {
            #pragma unroll
            for (int j = 0; j < 4; ++j)
                st4(&PART[w * (KD * 4) + (50 * j + l) * 4],
                    make_float4(acc[j][0], acc[j][1], acc[j][2], acc[j][3]));
        }
        __syncthreads();                   // B2: PART + pq partials ready

        // ---- q (combine; lam already folded), alpha, x/r update, rz partials ----
        float vr[2];
        if (stid) {
            float s0 = 0.f, s1 = 0.f;
            #pragma unroll
            for (int w8 = 0; w8 < 8; ++w8) {
                const float2 f = *(const float2*)&PART[w8 * (KD * 4) + r * 4 + sq * 2];
                s0 += f.x; s1 += f.y;
            }
            const float qv[2] = {s0, s1};
            #pragma unroll
            for (int j = 0; j < 2; ++j) {
                float pq = 0.f;
                #pragma unroll
                for (int w8 = 0; w8 < 8; ++w8) pq += WP1[w8][sq * 2 + j];
                const float alpha = rz4[j] / pq;
                xx[j] = fmaf(alpha, pp[j], xx[j]);
                rr[j] = fmaf(-alpha, qv[j], rr[j]);
                vr[j] = rr[j] * rr[j] * dinv[j];
            }
        } else {
            vr[0] = vr[1] = 0.f;
        }
        #pragma unroll
        for (int off = 2; off < 64; off <<= 1)
            #pragma unroll
            for (int j = 0; j < 2; ++j) vr[j] += __shfl_xor(vr[j], off, 64);
        if (l < 2) {
            #pragma unroll
            for (int j = 0; j < 2; ++j) WP2[w][l * 2 + j] = vr[j];
        }
        __syncthreads();                   // B3: rz ready

        // ---- beta, p update ----
        if (stid) {
            #pragma unroll
            for (int j = 0; j < 2; ++j) {
                float rzn = 0.f;
                #pragma unroll
                for (int w8 = 0; w8 < 8; ++w8) rzn += WP2[w8][sq * 2 + j];
                const float beta = rzn / rz4[j];
                rz4[j] = rzn;
                pp[j] = fmaf(beta, pp[j], rr[j] * dinv[j]);   // p = z + beta p
            }
            *(float2*)&P[r * 4 + sq * 2] = make_float2(pp[0], pp[1]);
        }
    }

    // ---- store x ----
    if (stid) {
        float* __restrict__ Ob = out + (size_t)(bK + i0 + sq * 2) * KD + r;
        Ob[0]  = xx[0];
        Ob[KD] = xx[1];
    }
}

extern "C" void kernel_launch(void* const* d_in, const int* in_sizes, int n_in,
                              void* d_out, int out_size, void* d_ws, size_t ws_size,
                              hipStream_t stream) {
    const float* A  = (const float*)d_in[0];
    const float* B  = (const float*)d_in[1];
    const float* ex = (const float*)d_in[2];
    const float* ey = (const float*)d_in[3];
    float* out = (float*)d_out;

    float* G = (float*)d_ws;
    float* R = G + 8 * KD * KD;

    dim3 grid1(4, 4, 16);
    gemm_gr_kernel<<<grid1, 256, 0, stream>>>(A, B, G, R);

    cg_kernel<<<400, 512, 0, stream>>>(G, R, ex, ey, out);
}

// Round 21
// 192.867 us; speedup vs baseline: 1.7002x; 1.0314x over previous
//
#include <hip/hip_runtime.h>
#include <math.h>

#define KD 200
#define CD 352
#define NITER 18
#define LMB 0.01f

__device__ __forceinline__ float4 ld4(const float* p) { return *(const float4*)p; }
__device__ __forceinline__ void st4(float* p, float4 v) { *(float4*)p = v; }
__device__ __forceinline__ float rdlane(float v, int lane) {
    return __int_as_float(__builtin_amdgcn_readlane(__float_as_int(v), lane));
}

// ---------------- Kernel 1: G = A A^T, R = B A^T (batched, 64x64 tiles) ----------------
__global__ __launch_bounds__(256) void gemm_gr_kernel(
    const float* __restrict__ A, const float* __restrict__ B,
    float* __restrict__ G, float* __restrict__ R)
{
    __shared__ __align__(16) float Ms[16][72];   // [k][m]
    __shared__ __align__(16) float Ns[16][72];   // [k][n]
    const int tid = threadIdx.x;
    const int z = blockIdx.z;
    const int b = z >> 1, which = z & 1;
    const float* __restrict__ Xb = (which ? B : A) + (size_t)b * KD * CD;
    const float* __restrict__ Ab = A + (size_t)b * KD * CD;
    float* __restrict__ O = (which ? R : G) + (size_t)b * KD * KD;
    const int tileM = blockIdx.y * 64;
    const int tileN = blockIdx.x * 64;

    const int lm = tid >> 2;             // 0..63
    const int kq = (tid & 3) * 4;        // 0,4,8,12
    const int rowM = min(tileM + lm, KD - 1);
    const int rowN = min(tileN + lm, KD - 1);
    const float* __restrict__ Xrow = Xb + (size_t)rowM * CD;
    const float* __restrict__ Arow = Ab + (size_t)rowN * CD;

    const int ty = tid >> 4, tx = tid & 15;
    const int m0 = ty * 4, n0 = tx * 4;

    float acc[4][4] = {};
    for (int kk = 0; kk < CD; kk += 16) {
        const float4 vx = ld4(Xrow + kk + kq);
        const float4 va = ld4(Arow + kk + kq);
        __syncthreads();
        Ms[kq + 0][lm] = vx.x; Ms[kq + 1][lm] = vx.y;
        Ms[kq + 2][lm] = vx.z; Ms[kq + 3][lm] = vx.w;
        Ns[kq + 0][lm] = va.x; Ns[kq + 1][lm] = va.y;
        Ns[kq + 2][lm] = va.z; Ns[kq + 3][lm] = va.w;
        __syncthreads();
        #pragma unroll
        for (int k = 0; k < 16; ++k) {
            const float4 am = ld4(&Ms[k][m0]);
            const float4 an = ld4(&Ns[k][n0]);
            acc[0][0] = fmaf(am.x, an.x, acc[0][0]);
            acc[0][1] = fmaf(am.x, an.y, acc[0][1]);
            acc[0][2] = fmaf(am.x, an.z, acc[0][2]);
            acc[0][3] = fmaf(am.x, an.w, acc[0][3]);
            acc[1][0] = fmaf(am.y, an.x, acc[1][0]);
            acc[1][1] = fmaf(am.y, an.y, acc[1][1]);
            acc[1][2] = fmaf(am.y, an.z, acc[1][2]);
            acc[1][3] = fmaf(am.y, an.w, acc[1][3]);
            acc[2][0] = fmaf(am.z, an.x, acc[2][0]);
            acc[2][1] = fmaf(am.z, an.y, acc[2][1]);
            acc[2][2] = fmaf(am.z, an.z, acc[2][2]);
            acc[2][3] = fmaf(am.z, an.w, acc[2][3]);
            acc[3][0] = fmaf(am.w, an.x, acc[3][0]);
            acc[3][1] = fmaf(am.w, an.y, acc[3][1]);
            acc[3][2] = fmaf(am.w, an.z, acc[3][2]);
            acc[3][3] = fmaf(am.w, an.w, acc[3][3]);
        }
    }
    const int gn = tileN + n0;
    if (gn < KD) {
        #pragma unroll
        for (int i = 0; i < 4; ++i) {
            const int gm = tileM + m0 + i;
            if (gm < KD)
                st4(&O[(size_t)gm * KD + gn],
                    make_float4(acc[i][0], acc[i][1], acc[i][2], acc[i][3]));
        }
    }
}

// ------- Kernel 2: batched single-reduction PCG, 4 systems/block, 3 barriers/iter -------
// R19 base (passed: VGPR 56, no spill, conflicts 0) with the two dependent reductions
// collapsed into ONE: rz_new = rz - 2a*S2 + a^2*S3 (EXACT identity; S2=sum d*r*q,
// S3=sum d*q^2 are computable before alpha, alongside pq). Unlike Gear (R9, diverged)
// alpha still uses the DIRECT pq dot; only rz uses a one-step exact recurrence.
// Matvec: R12/R19 proven pattern — rolled 8-column chunks, branch-free runtime-address
// P loads, COMPILE-TIME readlane indices (R18: runtime lane indices miscompute).
// Liveness bounded (<=32 G live; acc[4][4]) — far from the 128-VGPR spill cliff
// (R14/R16/R17). State thread tid<400 = (row r=tid>>1, sq=tid&1) owns systems
// sq*2..sq*2+1 in registers.
__global__ __launch_bounds__(512) void cg_kernel(
    const float* __restrict__ G, const float* __restrict__ R,
    const float* __restrict__ ex, const float* __restrict__ ey,
    float* __restrict__ out)
{
    __shared__ __align__(16) float P[864];             // p[c][s]=P[c*4+s], c<200,s<4 (+pad)
    __shared__ __align__(16) float PART[8 * KD * 4];   // [w][row][s], 25.6 KB
    __shared__ __align__(16) float WP[8][16];          // [w][sys*4 + {pq,S2,S3,pad}]
    __shared__ float red8[8];

    const int tid = threadIdx.x;
    const int w = tid >> 6, l = tid & 63;
    const int blk = blockIdx.x;
    const int b = blk / 50;                // 50 blocks per batch
    const int i0 = (blk - b * 50) * 4;
    const int bK = b * KD;
    const float* __restrict__ Gb = G + (size_t)b * KD * KD;

    // ---- scale = max(ex[b,:], ey[b,:]) ----
    float mxv = 0.f;
    if (tid < KD) mxv = fmaxf(ex[bK + tid], ey[bK + tid]);
    #pragma unroll
    for (int off = 32; off > 0; off >>= 1)
        mxv = fmaxf(mxv, __shfl_down(mxv, off, 64));
    if (l == 0) red8[w] = mxv;
    __syncthreads();
    float scale = red8[0];
    #pragma unroll
    for (int wv = 1; wv < 8; ++wv) scale = fmaxf(scale, red8[wv]);
    const float inv_scale = 1.0f / scale;

    const bool mact = (l < 50);
    const int gcol = mact ? l : 49;        // lanes 50..63 duplicate row-group 49 (discarded)

    // ---- state init (registers): thread owns (row r, systems sq*2..sq*2+1) ----
    const bool stid = tid < 400;
    const int r = tid >> 1, sq = tid & 1;
    float lam[2], dinv[2], rr[2], xx[2], pp[2], rz4[2];
    if (stid) {
        const float exj = ex[bK + r] * inv_scale;
        const float e1 = sqrtf(exj);
        const float gdiag = Gb[(size_t)r * KD + r];
        const float* __restrict__ Rb = R + (size_t)(bK + i0 + sq * 2) * KD + r;
        #pragma unroll
        for (int j = 0; j < 2; ++j) {
            const float eyi = ey[bK + i0 + sq * 2 + j] * inv_scale;
            const float e2 = sqrtf(eyi);
            const float dn = exj + eyi;
            const float re = e2 - e1;
            lam[j] = LMB * ((re * re + 1.f) / (dn * dn));
            dinv[j] = 1.f / (gdiag + lam[j]);
            rr[j] = Rb[(size_t)j * KD];
            pp[j] = rr[j] * dinv[j];      // p0 = z0
            xx[j] = 0.f;
        }
        *(float2*)&P[r * 4 + sq * 2] = make_float2(pp[0], pp[1]);
    }
    // rz0 partials (use WP slot 0)
    {
        float vg[2];
        #pragma unroll
        for (int j = 0; j < 2; ++j) vg[j] = stid ? rr[j] * pp[j] : 0.f;
        #pragma unroll
        for (int off = 2; off < 64; off <<= 1)
            #pragma unroll
            for (int j = 0; j < 2; ++j) vg[j] += __shfl_xor(vg[j], off, 64);
        if (l < 2) {
            #pragma unroll
            for (int j = 0; j < 2; ++j) WP[w][(l * 2 + j) * 4] = vg[j];
        }
    }
    __syncthreads();                       // P + rz0 partials ready
    if (stid) {
        #pragma unroll
        for (int j = 0; j < 2; ++j) {
            float s = 0.f;
            #pragma unroll
            for (int w8 = 0; w8 < 8; ++w8) s += WP[w8][(sq * 2 + j) * 4];
            rz4[j] = s;
        }
    }

    // ============ single-reduction PCG main loop (3 barriers/iter) ============
    for (int k = 0; k < NITER; ++k) {
        __syncthreads();                   // B1: P stable, WP consumed

        // ---- matvec partials over this wave's 25 columns (25w..25w+24) ----
        float acc[4][4];                   // [row group][system]
        #pragma unroll
        for (int j = 0; j < 4; ++j)
            #pragma unroll
            for (int s = 0; s < 4; ++s) acc[j][s] = 0.f;

        int base = 25 * w;
        #pragma unroll 1                   // rolled: bounds live G values to one chunk
        for (int ch = 0; ch < 3; ++ch) {
            const float pv = P[base * 4 + l];   // ALL lanes load (readlane hazard, R9/R10)
            const float* __restrict__ gp = Gb + (size_t)base * KD + gcol;
            #pragma unroll
            for (int dc = 0; dc < 8; ++dc) {
                const float g0v = gp[0];
                const float g1v = gp[50];
                const float g2v = gp[100];
                const float g3v = gp[150];
                #pragma unroll
                for (int s = 0; s < 4; ++s) {
                    const float ps = rdlane(pv, dc * 4 + s);   // compile-time index
                    acc[0][s] = fmaf(g0v, ps, acc[0][s]);
                    acc[1][s] = fmaf(g1v, ps, acc[1][s]);
                    acc[2][s] = fmaf(g2v, ps, acc[2][s]);
                    acc[3][s] = fmaf(g3v, ps, acc[3][s]);
                }
                gp += KD;
            }
            base += 8;
        }
        {   // trailing column 25w+24
            const float pv = P[base * 4 + l];
            const float* __restrict__ gp = Gb + (size_t)base * KD + gcol;
            const float g0v = gp[0];
            const float g1v = gp[50];
            const float g2v = gp[100];
            const float g3v = gp[150];
            #pragma unroll
            for (int s = 0; s < 4; ++s) {
                const float ps = rdlane(pv, s);
                acc[0][s] = fmaf(g0v, ps, acc[0][s]);
                acc[1][s] = fmaf(g1v, ps, acc[1][s]);
                acc[2][s] = fmaf(g2v, ps, acc[2][s]);
                acc[3][s] = fmaf(g3v, ps, acc[3][s]);
            }
        }
        if (mact) {
            #pragma unroll
            for (int j = 0; j < 4; ++j)
                st4(&PART[w * (KD * 4) + (50 * j + l) * 4],
                    make_float4(acc[j][0], acc[j][1], acc[j][2], acc[j][3]));
        }
        __syncthreads();                   // B2: PART ready

        // ---- combine q + ALL THREE dot partials (pq, S2, S3) in one phase ----
        float qq[2], vpq[2], vs2[2], vs3[2];
        if (stid) {
            float s0 = 0.f, s1 = 0.f;
            #pragma unroll
            for (int w8 = 0; w8 < 8; ++w8) {
                const float2 f = *(const float2*)&PART[w8 * (KD * 4) + r * 4 + sq * 2];
                s0 += f.x; s1 += f.y;
            }
            qq[0] = fmaf(lam[0], pp[0], s0);
            qq[1] = fmaf(lam[1], pp[1], s1);
            #pragma unroll
            for (int j = 0; j < 2; ++j) {
                vpq[j] = pp[j] * qq[j];
                vs2[j] = dinv[j] * rr[j] * qq[j];
                vs3[j] = dinv[j] * qq[j] * qq[j];
            }
        } else {
            qq[0] = qq[1] = 0.f;
            vpq[0] = vpq[1] = vs2[0] = vs2[1] = vs3[0] = vs3[1] = 0.f;
        }
        #pragma unroll
        for (int off = 2; off < 64; off <<= 1) {
            #pragma unroll
            for (int j = 0; j < 2; ++j) {
                vpq[j] += __shfl_xor(vpq[j], off, 64);
                vs2[j] += __shfl_xor(vs2[j], off, 64);
                vs3[j] += __shfl_xor(vs3[j], off, 64);
            }
        }
        if (l < 2) {
            #pragma unroll
            for (int j = 0; j < 2; ++j)
                st4(&WP[w][(l * 2 + j) * 4],
                    make_float4(vpq[j], vs2[j], vs3[j], 0.f));
        }
        __syncthreads();                   // B3: dots ready (the ONLY reduction barrier)

        // ---- all-scalar alpha/beta + x, r, p updates ----
        if (stid) {
            #pragma unroll
            for (int j = 0; j < 2; ++j) {
                float pq = 0.f, S2 = 0.f, S3 = 0.f;
                #pragma unroll
                for (int w8 = 0; w8 < 8; ++w8) {
                    const float4 f = ld4(&WP[w8][(sq * 2 + j) * 4]);   // broadcast
                    pq += f.x; S2 += f.y; S3 += f.z;
                }
                const float alpha = rz4[j] / pq;
                // rz_new = rz - 2a*S2 + a^2*S3  (exact expansion of sum d*(r-aq)^2)
                const float rzn = fmaf(alpha * alpha, S3, fmaf(-2.f * alpha, S2, rz4[j]));
                const float beta = rzn / rz4[j];
                rz4[j] = rzn;
                xx[j] = fmaf(alpha, pp[j], xx[j]);
                rr[j] = fmaf(-alpha, qq[j], rr[j]);
                pp[j] = fmaf(beta, pp[j], rr[j] * dinv[j]);   // p = z + beta p
            }
            *(float2*)&P[r * 4 + sq * 2] = make_float2(pp[0], pp[1]);
        }
    }

    // ---- store x ----
    if (stid) {
        float* __restrict__ Ob = out + (size_t)(bK + i0 + sq * 2) * KD + r;
        Ob[0]  = xx[0];
        Ob[KD] = xx[1];
    }
}

extern "C" void kernel_launch(void* const* d_in, const int* in_sizes, int n_in,
                              void* d_out, int out_size, void* d_ws, size_t ws_size,
                              hipStream_t stream) {
    const float* A  = (const float*)d_in[0];
    const float* B  = (const float*)d_in[1];
    const float* ex = (const float*)d_in[2];
    const float* ey = (const float*)d_in[3];
    float* out = (float*)d_out;

    float* G = (float*)d_ws;
    float* R = G + 8 * KD * KD;

    dim3 grid1(4, 4, 16);
    gemm_gr_kernel<<<grid1, 256, 0, stream>>>(A, B, G, R);

    cg_kernel<<<400, 512, 0, stream>>>(G, R, ex, ey, out);
}